// Round 6
// baseline (441.270 us; speedup 1.0000x reference)
//
#include <hip/hip_runtime.h>
#include <hip/hip_bf16.h>

#define B_  4
#define S_  2048
#define E_  1024
#define H_  16
#define DH_ 64
#define M_  (B_*S_)    // 8192 rows
#define HD_ (H_*DH_)   // 1024

typedef unsigned short u16;
typedef __attribute__((ext_vector_type(8))) __bf16 bf16x8;
typedef __attribute__((ext_vector_type(4))) __bf16 bf16x4;
typedef __attribute__((ext_vector_type(4))) float  f32x4;

#if __has_builtin(__builtin_amdgcn_exp2f)
#define EXP2F __builtin_amdgcn_exp2f
#else
#define EXP2F __builtin_exp2f
#endif

// softmax scale folded into Q at QKV epilogue: 1/sqrt(64) * log2(e)
#define QSCALE 0.18033688011112042f

// ---- async global->LDS, 16B per lane ----
__device__ __forceinline__ void g2l16(const void* g, void* l) {
  __builtin_amdgcn_global_load_lds(
      (const __attribute__((address_space(1))) void*)g,
      (__attribute__((address_space(3))) void*)l, 16, 0, 0);
}

// RNE float -> bf16 bits
__device__ __forceinline__ u16 f2bf(float f) {
  union { float f; unsigned u; } v; v.f = f;
  unsigned r = v.u + 0x7FFFu + ((v.u >> 16) & 1u);
  return (u16)(r >> 16);
}

// ---------------- conversion / packing kernels ----------------
__global__ __launch_bounds__(256) void cvt_x_kernel(const float* __restrict__ x,
                                                    u16* __restrict__ xb) {
  int i = blockIdx.x * 256 + threadIdx.x;
  float4 v = ((const float4*)x)[i];
  ushort4 o;
  o.x = f2bf(v.x); o.y = f2bf(v.y); o.z = f2bf(v.z); o.w = f2bf(v.w);
  ((ushort4*)xb)[i] = o;
}

__global__ __launch_bounds__(256) void pack_wqkv_kernel(
    const float* __restrict__ Wq, const float* __restrict__ Wk,
    const float* __restrict__ Wv, u16* __restrict__ wt) {
  __shared__ u16 tile[64][66];
  int p = blockIdx.z, h = blockIdx.y, e0 = blockIdx.x * 64;
  const float* src = (p == 0 ? Wq : (p == 1 ? Wk : Wv)) + h * (E_ * DH_);
  int tid = threadIdx.x;
#pragma unroll
  for (int r = 0; r < 16; ++r) {
    int idx = r * 256 + tid;
    int el = idx >> 6, d = idx & 63;
    tile[el][d] = f2bf(src[(e0 + el) * DH_ + d]);
  }
  __syncthreads();
  u16* dst = wt + (p * HD_ + h * DH_) * E_;
#pragma unroll
  for (int r = 0; r < 16; ++r) {
    int idx = r * 256 + tid;
    int d = idx >> 6, el = idx & 63;
    dst[d * E_ + e0 + el] = tile[el][d];
  }
}

__global__ __launch_bounds__(256) void pack_wo_kernel(const float* __restrict__ Wo,
                                                      u16* __restrict__ wt) {
  __shared__ u16 tile[64][66];
  int c0 = blockIdx.y * 64, e0 = blockIdx.x * 64;
  int tid = threadIdx.x;
#pragma unroll
  for (int r = 0; r < 16; ++r) {
    int idx = r * 256 + tid;
    int cl = idx >> 6, el = idx & 63;
    tile[cl][el] = f2bf(Wo[(c0 + cl) * E_ + e0 + el]);
  }
  __syncthreads();
#pragma unroll
  for (int r = 0; r < 16; ++r) {
    int idx = r * 256 + tid;
    int er = idx >> 6, cl = idx & 63;
    wt[(e0 + er) * HD_ + c0 + cl] = tile[cl][er];
  }
}

// ---- V transpose: [b,s,h,d] -> [b,h,d,s] (all stores/loads coalesced 16B) ----
__global__ __launch_bounds__(256) void transpose_v_kernel(
    const u16* __restrict__ vin, u16* __restrict__ vout) {
  __shared__ u16 t[64][72];
  const int tid = threadIdx.x;
  const int bh = blockIdx.y, st = blockIdx.x * 64;
  const u16* src = vin + ((size_t)((bh >> 4) * S_ + st)) * HD_ + (bh & 15) * 64;
#pragma unroll
  for (int rr = 0; rr < 2; ++rr) {
    int idx = rr * 256 + tid;
    int s = idx >> 3, ch = idx & 7;
    *(uint4*)&t[s][ch * 8] = *(const uint4*)(src + s * HD_ + ch * 8);
  }
  __syncthreads();
  u16* dst = vout + ((size_t)bh) * DH_ * S_ + st;
#pragma unroll
  for (int rr = 0; rr < 2; ++rr) {
    int idx = rr * 256 + tid;
    int d = idx >> 3, sc = (idx & 7) * 8;
    ushort4 o0, o1;
    o0.x = t[sc + 0][d]; o0.y = t[sc + 1][d]; o0.z = t[sc + 2][d]; o0.w = t[sc + 3][d];
    o1.x = t[sc + 4][d]; o1.y = t[sc + 5][d]; o1.z = t[sc + 6][d]; o1.w = t[sc + 7][d];
    *(ushort4*)(dst + (size_t)d * S_ + sc) = o0;
    *(ushort4*)(dst + (size_t)d * S_ + sc + 4) = o1;
  }
}

// ---------------- GEMM: C[M][N] = A[M][K] * Bt[N][K]^T, K = 1024 ----------------
// MODE 0: QKV epilogue — per-projection bias + bf16 store, coalesced [m][cc]
//         (b0=bq, b1=bk, b2=bv; V transposed later by transpose_v_kernel).
// MODE 1: out-proj epilogue (b0=bo; bias + fp32 store)
template <int MODE>
__global__ __launch_bounds__(256) void gemm_bt_kernel(
    const u16* __restrict__ A, const u16* __restrict__ Bt,
    const float* __restrict__ b0, const float* __restrict__ b1,
    const float* __restrict__ b2,
    u16* __restrict__ oQ, u16* __restrict__ oK, u16* __restrict__ oV,
    float* __restrict__ oF) {
  constexpr int K = 1024;
  __shared__ __align__(16) u16 As[128 * 32];
  __shared__ __align__(16) u16 Bs[128 * 32];
  const int tid = threadIdx.x;
  const int lane = tid & 63, wv = tid >> 6;
  const int wm = (wv >> 1) * 64, wn = (wv & 1) * 64;
  const int q4 = lane >> 4, lm = lane & 15;
  const int tileM = blockIdx.y * 128, tileN = blockIdx.x * 128;

  const int c0 = tid, c1 = tid + 256;
  const u16* gA0 = A + (tileM + (c0 >> 2)) * K + (((c0 & 3) ^ ((c0 >> 2) & 3)) * 8);
  const u16* gA1 = A + (tileM + (c1 >> 2)) * K + (((c1 & 3) ^ ((c1 >> 2) & 3)) * 8);
  const u16* gB0 = Bt + (tileN + (c0 >> 2)) * K + (((c0 & 3) ^ ((c0 >> 2) & 3)) * 8);
  const u16* gB1 = Bt + (tileN + (c1 >> 2)) * K + (((c1 & 3) ^ ((c1 >> 2) & 3)) * 8);
  u16* lA0 = As + c0 * 8; u16* lA1 = As + c1 * 8;
  u16* lB0 = Bs + c0 * 8; u16* lB1 = Bs + c1 * 8;

  f32x4 acc[4][4] = {};

  int aoff[4], boff[4];
#pragma unroll
  for (int i = 0; i < 4; ++i) {
    int ra = wm + i * 16 + lm;
    aoff[i] = ra * 32 + ((q4 ^ (ra & 3)) * 8);
    int rb = wn + i * 16 + lm;
    boff[i] = rb * 32 + ((q4 ^ (rb & 3)) * 8);
  }

  for (int k0 = 0; k0 < K; k0 += 32) {
    g2l16(gA0 + k0, lA0);
    g2l16(gA1 + k0, lA1);
    g2l16(gB0 + k0, lB0);
    g2l16(gB1 + k0, lB1);
    __syncthreads();
    bf16x8 af[4], bf[4];
#pragma unroll
    for (int i = 0; i < 4; ++i) af[i] = *(const bf16x8*)(As + aoff[i]);
#pragma unroll
    for (int j = 0; j < 4; ++j) bf[j] = *(const bf16x8*)(Bs + boff[j]);
#pragma unroll
    for (int i = 0; i < 4; ++i)
#pragma unroll
      for (int j = 0; j < 4; ++j)
        acc[i][j] = __builtin_amdgcn_mfma_f32_16x16x32_bf16(af[i], bf[j], acc[i][j], 0, 0, 0);
    __syncthreads();
  }

#pragma unroll
  for (int j = 0; j < 4; ++j) {
    int n = tileN + wn + j * 16 + lm;
    float bs;
    int proj = 0, cc = n;
    if (MODE == 1) {
      bs = b0[n];
    } else {
      proj = n >> 10; cc = n & 1023;   // proj uniform per block (tileN 128-aligned)
      const float* bp = (proj == 0 ? b0 : (proj == 1 ? b1 : b2));
      bs = bp[cc];
    }
#pragma unroll
    for (int i = 0; i < 4; ++i) {
#pragma unroll
      for (int r = 0; r < 4; ++r) {
        int m = tileM + wm + i * 16 + q4 * 4 + r;
        float val = acc[i][j][r] + bs;
        if (MODE == 1) {
          oF[m * HD_ + n] = val;
        } else {
          u16* optr = (proj == 0 ? oQ : (proj == 1 ? oK : oV));
          float scl = (proj == 0 ? QSCALE : 1.0f);
          optr[m * 1024 + cc] = f2bf(val * scl);
        }
      }
    }
  }
}

// ---------------- flash attention ----------------
// Block: 256 q-rows of one (b,h); wave wv owns q-rows [wv*64, wv*64+64), all keys.
// K/V double-buffered in LDS via global_load_lds (one barrier per tile).
// KEY PERMUTATION: K rows staged at LDS slot s hold logical key
// kperm(s) = (kb&1)*32 + q4*8 + (kb>>1)*4 + r  (s = kb*16+q4*4+r).
// With this order, the S^T-MFMA C-layout output IS the PV A-fragment layout
// per-lane (q=lm, keys q4*8+j), and V keeps sequential key order. So P never
// touches LDS: exp2 + cvt in registers, straight into the PV MFMA.
__global__ __launch_bounds__(256, 3) void flash_kernel(
    const u16* __restrict__ Q, const u16* __restrict__ Kb,
    const u16* __restrict__ Vt, u16* __restrict__ Z) {
  __shared__ __align__(16) u16 Ks[2][64 * 64];   // [slot][d] swizzled, key-permuted
  __shared__ __align__(16) u16 Vs[2][64 * 64];   // [d][key] swizzled, sequential
  const int tid = threadIdx.x, lane = tid & 63, wv = tid >> 6;
  const int q4 = lane >> 4, lm = lane & 15;

  const int bid = blockIdx.x;
  const int bh = bid >> 3, qt = bid & 7;         // 8 consecutive blocks share (b,h) K/V
  const int b = bh >> 4, h = bh & 15;

  const u16* qbase = Q + ((size_t)(b * S_ + qt * 256)) * HD_ + h * DH_;
  const u16* kbase = Kb + (size_t)b * S_ * HD_ + h * DH_;
  const u16* vbase = Vt + ((size_t)(b * H_ + h)) * DH_ * S_;
  u16* zbase = Z + ((size_t)(b * S_ + qt * 256)) * HD_ + h * DH_;

  // staging thread coords (slot row, swizzled source chunk), 2 rounds of 256
  const int c0 = tid,       r0 = c0 >> 3, s0 = ((c0 & 7) ^ (r0 & 7)) * 8;
  const int c1 = tid + 256, r1 = c1 >> 3, s1 = ((c1 & 7) ^ (r1 & 7)) * 8;
  // key permutation for K staging rows
  const int kr0 = ((r0 >> 4) & 1) * 32 + ((r0 >> 2) & 3) * 8 + (r0 >> 5) * 4 + (r0 & 3);
  const int kr1 = ((r1 >> 4) & 1) * 32 + ((r1 >> 2) & 3) * 8 + (r1 >> 5) * 4 + (r1 & 3);

  // persistent Q B-frags: q-row = wv*64 + qs*16 + lm, d = dc*32 + q4*8 ..+7
  bf16x8 qf[4][2];
#pragma unroll
  for (int qs = 0; qs < 4; ++qs)
#pragma unroll
    for (int dc = 0; dc < 2; ++dc)
      qf[qs][dc] = *(const bf16x8*)(qbase + (wv * 64 + qs * 16 + lm) * HD_ + dc * 32 + q4 * 8);

  const bf16x8 ones = {(__bf16)1.f, (__bf16)1.f, (__bf16)1.f, (__bf16)1.f,
                       (__bf16)1.f, (__bf16)1.f, (__bf16)1.f, (__bf16)1.f};

  // lane-constant LDS offsets (u16 units)
  int koff[4][2], voff[2][4];
#pragma unroll
  for (int kb = 0; kb < 4; ++kb)
#pragma unroll
    for (int dc = 0; dc < 2; ++dc) {
      int row = kb * 16 + lm;
      koff[kb][dc] = row * 64 + (((dc * 4 + q4) ^ (row & 7)) * 8);
    }
#pragma unroll
  for (int ck = 0; ck < 2; ++ck)
#pragma unroll
    for (int db = 0; db < 4; ++db) {
      int row = db * 16 + lm;
      voff[ck][db] = row * 64 + (((ck * 4 + q4) ^ (row & 7)) * 8);
    }

  f32x4 oacc[4][4] = {};
  f32x4 liacc[4] = {};

  // stage tile 0 into buffer 0
  {
    g2l16(kbase + kr0 * HD_ + s0, Ks[0] + c0 * 8);
    g2l16(kbase + kr1 * HD_ + s1, Ks[0] + c1 * 8);
    g2l16(vbase + r0 * S_ + s0, Vs[0] + c0 * 8);
    g2l16(vbase + r1 * S_ + s1, Vs[0] + c1 * 8);
  }

  for (int t = 0; t < 32; ++t) {
    const int pb = t & 1;
    __syncthreads();                      // staging of tile t complete
    if (t < 31) {                         // prefetch tile t+1 into the other buffer
      const u16* kt = kbase + (size_t)(t + 1) * 64 * HD_;
      const u16* vt = vbase + (t + 1) * 64;
      g2l16(kt + kr0 * HD_ + s0, Ks[1 - pb] + c0 * 8);
      g2l16(kt + kr1 * HD_ + s1, Ks[1 - pb] + c1 * 8);
      g2l16(vt + r0 * S_ + s0, Vs[1 - pb] + c0 * 8);
      g2l16(vt + r1 * S_ + s1, Vs[1 - pb] + c1 * 8);
    }
    const u16* Kp = Ks[pb];
    const u16* Vp = Vs[pb];

    // ---- S^T = K·Q^T (rows = permuted key slots, cols = q), exp2 in regs ----
    bf16x4 pfr[4][4];   // [qs][kb] : 4 consecutive logical keys each
#pragma unroll
    for (int kb = 0; kb < 4; ++kb) {
      bf16x8 k0 = *(const bf16x8*)(Kp + koff[kb][0]);
      bf16x8 k1 = *(const bf16x8*)(Kp + koff[kb][1]);
#pragma unroll
      for (int qs = 0; qs < 4; ++qs) {
        f32x4 sc = {};
        sc = __builtin_amdgcn_mfma_f32_16x16x32_bf16(k0, qf[qs][0], sc, 0, 0, 0);
        sc = __builtin_amdgcn_mfma_f32_16x16x32_bf16(k1, qf[qs][1], sc, 0, 0, 0);
        f32x4 p;
#pragma unroll
        for (int r = 0; r < 4; ++r) p[r] = EXP2F(sc[r]);
        pfr[qs][kb] = __builtin_convertvector(p, bf16x4);
      }
    }

    // ---- O += P·V ; li += P·1  (P A-frags assembled purely in registers) ----
#pragma unroll
    for (int ck = 0; ck < 2; ++ck) {
      bf16x8 pf[4];
#pragma unroll
      for (int qs = 0; qs < 4; ++qs)
        pf[qs] = __builtin_shufflevector(pfr[qs][ck], pfr[qs][ck + 2],
                                         0, 1, 2, 3, 4, 5, 6, 7);
#pragma unroll
      for (int qs = 0; qs < 4; ++qs)
        liacc[qs] = __builtin_amdgcn_mfma_f32_16x16x32_bf16(pf[qs], ones, liacc[qs], 0, 0, 0);
#pragma unroll
      for (int db = 0; db < 4; ++db) {
        bf16x8 vf = *(const bf16x8*)(Vp + voff[ck][db]);
#pragma unroll
        for (int qs = 0; qs < 4; ++qs)
          oacc[qs][db] = __builtin_amdgcn_mfma_f32_16x16x32_bf16(pf[qs], vf, oacc[qs][db], 0, 0, 0);
      }
    }
  }

  // ---- normalize + store (wave owns its 64 q-rows; li is in-lane) ----
#pragma unroll
  for (int qs = 0; qs < 4; ++qs) {
    float rin[4];
#pragma unroll
    for (int r = 0; r < 4; ++r) rin[r] = 1.f / liacc[qs][r];
#pragma unroll
    for (int db = 0; db < 4; ++db)
#pragma unroll
      for (int r = 0; r < 4; ++r)
        zbase[(wv * 64 + qs * 16 + q4 * 4 + r) * HD_ + db * 16 + lm] =
            f2bf(oacc[qs][db][r] * rin[r]);
  }
}

// ---------------- host ----------------
extern "C" void kernel_launch(void* const* d_in, const int* in_sizes, int n_in,
                              void* d_out, int out_size, void* d_ws, size_t ws_size,
                              hipStream_t stream) {
  const float* x  = (const float*)d_in[0];
  const float* Wq = (const float*)d_in[1];
  const float* bq = (const float*)d_in[2];
  const float* Wk = (const float*)d_in[3];
  const float* bk = (const float*)d_in[4];
  const float* Wv = (const float*)d_in[5];
  const float* bv = (const float*)d_in[6];
  const float* Wo = (const float*)d_in[7];
  const float* bo = (const float*)d_in[8];
  float* out = (float*)d_out;

  char* w = (char*)d_ws;
  u16*   xb    = (u16*)w;   w += (size_t)M_ * E_ * 2;
  u16*   wqkvT = (u16*)w;   w += (size_t)3 * HD_ * E_ * 2;
  u16*   woT   = (u16*)w;   w += (size_t)E_ * HD_ * 2;
  u16*   qB    = (u16*)w;   w += (size_t)M_ * HD_ * 2;
  u16*   kB    = (u16*)w;   w += (size_t)M_ * HD_ * 2;
  u16*   vT    = (u16*)w;   w += (size_t)M_ * HD_ * 2;
  u16*   zB    = (u16*)w;   w += (size_t)M_ * HD_ * 2;
  // vB ([b,s,h,d] pre-transpose V) aliases zB: consumed by transpose_v before
  // flash writes zB.
  u16*   vB    = zB;

  cvt_x_kernel<<<dim3(M_ * E_ / 4 / 256), 256, 0, stream>>>(x, xb);
  pack_wqkv_kernel<<<dim3(16, 16, 3), 256, 0, stream>>>(Wq, Wk, Wv, wqkvT);
  pack_wo_kernel<<<dim3(16, 16), 256, 0, stream>>>(Wo, woT);
  gemm_bt_kernel<0><<<dim3(24, 64), 256, 0, stream>>>(xb, wqkvT, bq, bk, bv,
                                                      qB, kB, vB, nullptr);
  transpose_v_kernel<<<dim3(32, 64), 256, 0, stream>>>(vB, vT);
  flash_kernel<<<dim3(512), 256, 0, stream>>>(qB, kB, vT, zB);
  gemm_bt_kernel<1><<<dim3(8, 64), 256, 0, stream>>>(zB, woT, bo, nullptr, nullptr,
                                                     nullptr, nullptr, nullptr, out);
}

// Round 7
// 284.099 us; speedup vs baseline: 1.5532x; 1.5532x over previous
//
#include <hip/hip_runtime.h>
#include <hip/hip_bf16.h>

#define B_  4
#define S_  2048
#define E_  1024
#define H_  16
#define DH_ 64
#define M_  (B_*S_)    // 8192 rows
#define HD_ (H_*DH_)   // 1024

typedef unsigned short u16;
typedef __attribute__((ext_vector_type(8))) __bf16 bf16x8;
typedef __attribute__((ext_vector_type(4))) __bf16 bf16x4;
typedef __attribute__((ext_vector_type(4))) float  f32x4;

#if __has_builtin(__builtin_amdgcn_exp2f)
#define EXP2F __builtin_amdgcn_exp2f
#else
#define EXP2F __builtin_exp2f
#endif

// softmax scale folded into Q at QKV epilogue: 1/sqrt(64) * log2(e)
#define QSCALE 0.18033688011112042f

// ---- async global->LDS, 16B per lane ----
__device__ __forceinline__ void g2l16(const void* g, void* l) {
  __builtin_amdgcn_global_load_lds(
      (const __attribute__((address_space(1))) void*)g,
      (__attribute__((address_space(3))) void*)l, 16, 0, 0);
}

// RNE float -> bf16 bits
__device__ __forceinline__ u16 f2bf(float f) {
  union { float f; unsigned u; } v; v.f = f;
  unsigned r = v.u + 0x7FFFu + ((v.u >> 16) & 1u);
  return (u16)(r >> 16);
}

// ---------------- conversion / packing kernels ----------------
__global__ __launch_bounds__(256) void cvt_x_kernel(const float* __restrict__ x,
                                                    u16* __restrict__ xb) {
  int i = blockIdx.x * 256 + threadIdx.x;
  float4 v = ((const float4*)x)[i];
  ushort4 o;
  o.x = f2bf(v.x); o.y = f2bf(v.y); o.z = f2bf(v.z); o.w = f2bf(v.w);
  ((ushort4*)xb)[i] = o;
}

__global__ __launch_bounds__(256) void pack_wqkv_kernel(
    const float* __restrict__ Wq, const float* __restrict__ Wk,
    const float* __restrict__ Wv, u16* __restrict__ wt) {
  __shared__ u16 tile[64][66];
  int p = blockIdx.z, h = blockIdx.y, e0 = blockIdx.x * 64;
  const float* src = (p == 0 ? Wq : (p == 1 ? Wk : Wv)) + h * (E_ * DH_);
  int tid = threadIdx.x;
#pragma unroll
  for (int r = 0; r < 16; ++r) {
    int idx = r * 256 + tid;
    int el = idx >> 6, d = idx & 63;
    tile[el][d] = f2bf(src[(e0 + el) * DH_ + d]);
  }
  __syncthreads();
  u16* dst = wt + (p * HD_ + h * DH_) * E_;
#pragma unroll
  for (int r = 0; r < 16; ++r) {
    int idx = r * 256 + tid;
    int d = idx >> 6, el = idx & 63;
    dst[d * E_ + e0 + el] = tile[el][d];
  }
}

__global__ __launch_bounds__(256) void pack_wo_kernel(const float* __restrict__ Wo,
                                                      u16* __restrict__ wt) {
  __shared__ u16 tile[64][66];
  int c0 = blockIdx.y * 64, e0 = blockIdx.x * 64;
  int tid = threadIdx.x;
#pragma unroll
  for (int r = 0; r < 16; ++r) {
    int idx = r * 256 + tid;
    int cl = idx >> 6, el = idx & 63;
    tile[cl][el] = f2bf(Wo[(c0 + cl) * E_ + e0 + el]);
  }
  __syncthreads();
#pragma unroll
  for (int r = 0; r < 16; ++r) {
    int idx = r * 256 + tid;
    int er = idx >> 6, cl = idx & 63;
    wt[(e0 + er) * HD_ + c0 + cl] = tile[cl][er];
  }
}

// ---- V transpose: [b,s,h,d] -> [b,h,d,s] (all stores/loads coalesced 16B) ----
__global__ __launch_bounds__(256) void transpose_v_kernel(
    const u16* __restrict__ vin, u16* __restrict__ vout) {
  __shared__ u16 t[64][72];
  const int tid = threadIdx.x;
  const int bh = blockIdx.y, st = blockIdx.x * 64;
  const u16* src = vin + ((size_t)((bh >> 4) * S_ + st)) * HD_ + (bh & 15) * 64;
#pragma unroll
  for (int rr = 0; rr < 2; ++rr) {
    int idx = rr * 256 + tid;
    int s = idx >> 3, ch = idx & 7;
    *(uint4*)&t[s][ch * 8] = *(const uint4*)(src + s * HD_ + ch * 8);
  }
  __syncthreads();
  u16* dst = vout + ((size_t)bh) * DH_ * S_ + st;
#pragma unroll
  for (int rr = 0; rr < 2; ++rr) {
    int idx = rr * 256 + tid;
    int d = idx >> 3, sc = (idx & 7) * 8;
    ushort4 o0, o1;
    o0.x = t[sc + 0][d]; o0.y = t[sc + 1][d]; o0.z = t[sc + 2][d]; o0.w = t[sc + 3][d];
    o1.x = t[sc + 4][d]; o1.y = t[sc + 5][d]; o1.z = t[sc + 6][d]; o1.w = t[sc + 7][d];
    *(ushort4*)(dst + (size_t)d * S_ + sc) = o0;
    *(ushort4*)(dst + (size_t)d * S_ + sc + 4) = o1;
  }
}

// ---------------- GEMM: C[M][N] = A[M][K] * Bt[N][K]^T, K = 1024 ----------------
// MODE 0: QKV epilogue — per-projection bias + bf16 store, coalesced [m][cc]
//         (b0=bq, b1=bk, b2=bv; V transposed later by transpose_v_kernel).
// MODE 1: out-proj epilogue (b0=bo; bias + fp32 store)
template <int MODE>
__global__ __launch_bounds__(256) void gemm_bt_kernel(
    const u16* __restrict__ A, const u16* __restrict__ Bt,
    const float* __restrict__ b0, const float* __restrict__ b1,
    const float* __restrict__ b2,
    u16* __restrict__ oQ, u16* __restrict__ oK, u16* __restrict__ oV,
    float* __restrict__ oF) {
  constexpr int K = 1024;
  __shared__ __align__(16) u16 As[128 * 32];
  __shared__ __align__(16) u16 Bs[128 * 32];
  const int tid = threadIdx.x;
  const int lane = tid & 63, wv = tid >> 6;
  const int wm = (wv >> 1) * 64, wn = (wv & 1) * 64;
  const int q4 = lane >> 4, lm = lane & 15;
  const int tileM = blockIdx.y * 128, tileN = blockIdx.x * 128;

  const int c0 = tid, c1 = tid + 256;
  const u16* gA0 = A + (tileM + (c0 >> 2)) * K + (((c0 & 3) ^ ((c0 >> 2) & 3)) * 8);
  const u16* gA1 = A + (tileM + (c1 >> 2)) * K + (((c1 & 3) ^ ((c1 >> 2) & 3)) * 8);
  const u16* gB0 = Bt + (tileN + (c0 >> 2)) * K + (((c0 & 3) ^ ((c0 >> 2) & 3)) * 8);
  const u16* gB1 = Bt + (tileN + (c1 >> 2)) * K + (((c1 & 3) ^ ((c1 >> 2) & 3)) * 8);
  u16* lA0 = As + c0 * 8; u16* lA1 = As + c1 * 8;
  u16* lB0 = Bs + c0 * 8; u16* lB1 = Bs + c1 * 8;

  f32x4 acc[4][4] = {};

  int aoff[4], boff[4];
#pragma unroll
  for (int i = 0; i < 4; ++i) {
    int ra = wm + i * 16 + lm;
    aoff[i] = ra * 32 + ((q4 ^ (ra & 3)) * 8);
    int rb = wn + i * 16 + lm;
    boff[i] = rb * 32 + ((q4 ^ (rb & 3)) * 8);
  }

  for (int k0 = 0; k0 < K; k0 += 32) {
    g2l16(gA0 + k0, lA0);
    g2l16(gA1 + k0, lA1);
    g2l16(gB0 + k0, lB0);
    g2l16(gB1 + k0, lB1);
    __syncthreads();
    bf16x8 af[4], bf[4];
#pragma unroll
    for (int i = 0; i < 4; ++i) af[i] = *(const bf16x8*)(As + aoff[i]);
#pragma unroll
    for (int j = 0; j < 4; ++j) bf[j] = *(const bf16x8*)(Bs + boff[j]);
#pragma unroll
    for (int i = 0; i < 4; ++i)
#pragma unroll
      for (int j = 0; j < 4; ++j)
        acc[i][j] = __builtin_amdgcn_mfma_f32_16x16x32_bf16(af[i], bf[j], acc[i][j], 0, 0, 0);
    __syncthreads();
  }

#pragma unroll
  for (int j = 0; j < 4; ++j) {
    int n = tileN + wn + j * 16 + lm;
    float bs;
    int proj = 0, cc = n;
    if (MODE == 1) {
      bs = b0[n];
    } else {
      proj = n >> 10; cc = n & 1023;   // proj uniform per block (tileN 128-aligned)
      const float* bp = (proj == 0 ? b0 : (proj == 1 ? b1 : b2));
      bs = bp[cc];
    }
#pragma unroll
    for (int i = 0; i < 4; ++i) {
#pragma unroll
      for (int r = 0; r < 4; ++r) {
        int m = tileM + wm + i * 16 + q4 * 4 + r;
        float val = acc[i][j][r] + bs;
        if (MODE == 1) {
          oF[m * HD_ + n] = val;
        } else {
          u16* optr = (proj == 0 ? oQ : (proj == 1 ? oK : oV));
          float scl = (proj == 0 ? QSCALE : 1.0f);
          optr[m * 1024 + cc] = f2bf(val * scl);
        }
      }
    }
  }
}

// ---------------- flash attention ----------------
// Block: 256 q-rows of one (b,h); wave wv owns q-rows [wv*64, wv*64+64), all keys.
// K/V double-buffered in LDS via global_load_lds (one barrier per tile).
// KEY PERMUTATION: K rows staged at LDS slot s = kb*16+q4*4+r hold logical key
// kperm(s) = (kb&1)*32 + q4*8 + (kb>>1)*4 + r. With this order, the S^T-MFMA
// C-layout output IS the PV A-fragment layout per-lane (q=lm, keys ck*32+q4*8+j),
// and V keeps sequential key order. P never touches LDS.
// Interleaved per key-chunk (ck needs kb=ck and kb=ck+2) to cap register
// liveness; __launch_bounds__(256,2) — (256,3) forced spills (R6: 493 MB
// scratch WRITE_SIZE, 2.6x regression).
__global__ __launch_bounds__(256, 2) void flash_kernel(
    const u16* __restrict__ Q, const u16* __restrict__ Kb,
    const u16* __restrict__ Vt, u16* __restrict__ Z) {
  __shared__ __align__(16) u16 Ks[2][64 * 64];   // [slot][d] swizzled, key-permuted
  __shared__ __align__(16) u16 Vs[2][64 * 64];   // [d][key] swizzled, sequential
  const int tid = threadIdx.x, lane = tid & 63, wv = tid >> 6;
  const int q4 = lane >> 4, lm = lane & 15;

  const int bid = blockIdx.x;
  const int bh = bid >> 3, qt = bid & 7;         // 8 consecutive blocks share (b,h) K/V
  const int b = bh >> 4, h = bh & 15;

  const u16* qbase = Q + ((size_t)(b * S_ + qt * 256)) * HD_ + h * DH_;
  const u16* kbase = Kb + (size_t)b * S_ * HD_ + h * DH_;
  const u16* vbase = Vt + ((size_t)(b * H_ + h)) * DH_ * S_;
  u16* zbase = Z + ((size_t)(b * S_ + qt * 256)) * HD_ + h * DH_;

  // staging thread coords (slot row, swizzled source chunk), 2 rounds of 256
  const int c0 = tid,       r0 = c0 >> 3, s0 = ((c0 & 7) ^ (r0 & 7)) * 8;
  const int c1 = tid + 256, r1 = c1 >> 3, s1 = ((c1 & 7) ^ (r1 & 7)) * 8;
  // key permutation for K staging rows
  const int kr0 = ((r0 >> 4) & 1) * 32 + ((r0 >> 2) & 3) * 8 + (r0 >> 5) * 4 + (r0 & 3);
  const int kr1 = ((r1 >> 4) & 1) * 32 + ((r1 >> 2) & 3) * 8 + (r1 >> 5) * 4 + (r1 & 3);

  // persistent Q B-frags: q-row = wv*64 + qs*16 + lm, d = dc*32 + q4*8 ..+7
  bf16x8 qf[4][2];
#pragma unroll
  for (int qs = 0; qs < 4; ++qs)
#pragma unroll
    for (int dc = 0; dc < 2; ++dc)
      qf[qs][dc] = *(const bf16x8*)(qbase + (wv * 64 + qs * 16 + lm) * HD_ + dc * 32 + q4 * 8);

  const bf16x8 ones = {(__bf16)1.f, (__bf16)1.f, (__bf16)1.f, (__bf16)1.f,
                       (__bf16)1.f, (__bf16)1.f, (__bf16)1.f, (__bf16)1.f};

  // lane-constant LDS offsets (u16 units)
  int koff[4][2], voff[2][4];
#pragma unroll
  for (int kb = 0; kb < 4; ++kb)
#pragma unroll
    for (int dc = 0; dc < 2; ++dc) {
      int row = kb * 16 + lm;
      koff[kb][dc] = row * 64 + (((dc * 4 + q4) ^ (row & 7)) * 8);
    }
#pragma unroll
  for (int ck = 0; ck < 2; ++ck)
#pragma unroll
    for (int db = 0; db < 4; ++db) {
      int row = db * 16 + lm;
      voff[ck][db] = row * 64 + (((ck * 4 + q4) ^ (row & 7)) * 8);
    }

  f32x4 oacc[4][4] = {};
  f32x4 liacc[4] = {};

  // stage tile 0 into buffer 0
  {
    g2l16(kbase + kr0 * HD_ + s0, Ks[0] + c0 * 8);
    g2l16(kbase + kr1 * HD_ + s1, Ks[0] + c1 * 8);
    g2l16(vbase + r0 * S_ + s0, Vs[0] + c0 * 8);
    g2l16(vbase + r1 * S_ + s1, Vs[0] + c1 * 8);
  }

  for (int t = 0; t < 32; ++t) {
    const int pb = t & 1;
    __syncthreads();                      // staging of tile t complete
    if (t < 31) {                         // prefetch tile t+1 into the other buffer
      const u16* kt = kbase + (size_t)(t + 1) * 64 * HD_;
      const u16* vt = vbase + (t + 1) * 64;
      g2l16(kt + kr0 * HD_ + s0, Ks[1 - pb] + c0 * 8);
      g2l16(kt + kr1 * HD_ + s1, Ks[1 - pb] + c1 * 8);
      g2l16(vt + r0 * S_ + s0, Vs[1 - pb] + c0 * 8);
      g2l16(vt + r1 * S_ + s1, Vs[1 - pb] + c1 * 8);
    }
    const u16* Kp = Ks[pb];
    const u16* Vp = Vs[pb];

    // ---- per key-chunk ck (32 keys): S^T via kb={ck,ck+2}, exp2 in regs,
    //      then immediately PV — keeps only pf[4] live, not all 16 frags ----
#pragma unroll
    for (int ck = 0; ck < 2; ++ck) {
      bf16x8 ka0 = *(const bf16x8*)(Kp + koff[ck][0]);
      bf16x8 ka1 = *(const bf16x8*)(Kp + koff[ck][1]);
      bf16x8 kb0 = *(const bf16x8*)(Kp + koff[ck + 2][0]);
      bf16x8 kb1 = *(const bf16x8*)(Kp + koff[ck + 2][1]);
      bf16x8 pf[4];
#pragma unroll
      for (int qs = 0; qs < 4; ++qs) {
        f32x4 sa = {}, sb = {};
        sa = __builtin_amdgcn_mfma_f32_16x16x32_bf16(ka0, qf[qs][0], sa, 0, 0, 0);
        sa = __builtin_amdgcn_mfma_f32_16x16x32_bf16(ka1, qf[qs][1], sa, 0, 0, 0);
        sb = __builtin_amdgcn_mfma_f32_16x16x32_bf16(kb0, qf[qs][0], sb, 0, 0, 0);
        sb = __builtin_amdgcn_mfma_f32_16x16x32_bf16(kb1, qf[qs][1], sb, 0, 0, 0);
        f32x4 pa, pb2;
#pragma unroll
        for (int r = 0; r < 4; ++r) { pa[r] = EXP2F(sa[r]); pb2[r] = EXP2F(sb[r]); }
        bf16x4 la = __builtin_convertvector(pa, bf16x4);
        bf16x4 lb = __builtin_convertvector(pb2, bf16x4);
        pf[qs] = __builtin_shufflevector(la, lb, 0, 1, 2, 3, 4, 5, 6, 7);
      }
#pragma unroll
      for (int qs = 0; qs < 4; ++qs)
        liacc[qs] = __builtin_amdgcn_mfma_f32_16x16x32_bf16(pf[qs], ones, liacc[qs], 0, 0, 0);
#pragma unroll
      for (int db = 0; db < 4; ++db) {
        bf16x8 vf = *(const bf16x8*)(Vp + voff[ck][db]);
#pragma unroll
        for (int qs = 0; qs < 4; ++qs)
          oacc[qs][db] = __builtin_amdgcn_mfma_f32_16x16x32_bf16(pf[qs], vf, oacc[qs][db], 0, 0, 0);
      }
    }
  }

  // ---- normalize + store (wave owns its 64 q-rows; li is in-lane) ----
#pragma unroll
  for (int qs = 0; qs < 4; ++qs) {
    float rin[4];
#pragma unroll
    for (int r = 0; r < 4; ++r) rin[r] = 1.f / liacc[qs][r];
#pragma unroll
    for (int db = 0; db < 4; ++db)
#pragma unroll
      for (int r = 0; r < 4; ++r)
        zbase[(wv * 64 + qs * 16 + q4 * 4 + r) * HD_ + db * 16 + lm] =
            f2bf(oacc[qs][db][r] * rin[r]);
  }
}

// ---------------- host ----------------
extern "C" void kernel_launch(void* const* d_in, const int* in_sizes, int n_in,
                              void* d_out, int out_size, void* d_ws, size_t ws_size,
                              hipStream_t stream) {
  const float* x  = (const float*)d_in[0];
  const float* Wq = (const float*)d_in[1];
  const float* bq = (const float*)d_in[2];
  const float* Wk = (const float*)d_in[3];
  const float* bk = (const float*)d_in[4];
  const float* Wv = (const float*)d_in[5];
  const float* bv = (const float*)d_in[6];
  const float* Wo = (const float*)d_in[7];
  const float* bo = (const float*)d_in[8];
  float* out = (float*)d_out;

  char* w = (char*)d_ws;
  u16*   xb    = (u16*)w;   w += (size_t)M_ * E_ * 2;
  u16*   wqkvT = (u16*)w;   w += (size_t)3 * HD_ * E_ * 2;
  u16*   woT   = (u16*)w;   w += (size_t)E_ * HD_ * 2;
  u16*   qB    = (u16*)w;   w += (size_t)M_ * HD_ * 2;
  u16*   kB    = (u16*)w;   w += (size_t)M_ * HD_ * 2;
  u16*   vT    = (u16*)w;   w += (size_t)M_ * HD_ * 2;
  u16*   zB    = (u16*)w;   w += (size_t)M_ * HD_ * 2;
  // vB ([b,s,h,d] pre-transpose V) aliases zB: consumed by transpose_v before
  // flash writes zB.
  u16*   vB    = zB;

  cvt_x_kernel<<<dim3(M_ * E_ / 4 / 256), 256, 0, stream>>>(x, xb);
  pack_wqkv_kernel<<<dim3(16, 16, 3), 256, 0, stream>>>(Wq, Wk, Wv, wqkvT);
  pack_wo_kernel<<<dim3(16, 16), 256, 0, stream>>>(Wo, woT);
  gemm_bt_kernel<0><<<dim3(24, 64), 256, 0, stream>>>(xb, wqkvT, bq, bk, bv,
                                                      qB, kB, vB, nullptr);
  transpose_v_kernel<<<dim3(32, 64), 256, 0, stream>>>(vB, vT);
  flash_kernel<<<dim3(512), 256, 0, stream>>>(qB, kB, vT, zB);
  gemm_bt_kernel<1><<<dim3(8, 64), 256, 0, stream>>>(zB, woT, bo, nullptr, nullptr,
                                                     nullptr, nullptr, nullptr, out);
}

// Round 8
// 266.466 us; speedup vs baseline: 1.6560x; 1.0662x over previous
//
#include <hip/hip_runtime.h>
#include <hip/hip_bf16.h>

#define B_  4
#define S_  2048
#define E_  1024
#define H_  16
#define DH_ 64
#define M_  (B_*S_)    // 8192 rows
#define HD_ (H_*DH_)   // 1024

typedef unsigned short u16;
typedef __attribute__((ext_vector_type(8))) __bf16 bf16x8;
typedef __attribute__((ext_vector_type(4))) __bf16 bf16x4;
typedef __attribute__((ext_vector_type(4))) float  f32x4;

#if __has_builtin(__builtin_amdgcn_exp2f)
#define EXP2F __builtin_amdgcn_exp2f
#else
#define EXP2F __builtin_exp2f
#endif

// softmax scale folded into Q at QKV epilogue: 1/sqrt(64) * log2(e)
#define QSCALE 0.18033688011112042f

// ---- async global->LDS, 16B per lane ----
__device__ __forceinline__ void g2l16(const void* g, void* l) {
  __builtin_amdgcn_global_load_lds(
      (const __attribute__((address_space(1))) void*)g,
      (__attribute__((address_space(3))) void*)l, 16, 0, 0);
}

// RNE float -> bf16 bits (scalar path, used in prep only)
__device__ __forceinline__ u16 f2bf(float f) {
  union { float f; unsigned u; } v; v.f = f;
  unsigned r = v.u + 0x7FFFu + ((v.u >> 16) & 1u);
  return (u16)(r >> 16);
}

// ---------------- fused prep: cvt_x | pack_wqkv | pack_wo ----------------
// blocks [0,8192): x fp32 -> bf16
// blocks [8192,8960): Wq/Wk/Wv [h,e,d] -> wqkvT [p*1024+h*64+d][e] bf16
// blocks [8960,9216): Wo [c,e] -> woT [e][c] bf16
__global__ __launch_bounds__(256) void prep_kernel(
    const float* __restrict__ x, const float* __restrict__ Wq,
    const float* __restrict__ Wk, const float* __restrict__ Wv,
    const float* __restrict__ Wo,
    u16* __restrict__ xb, u16* __restrict__ wqkvT, u16* __restrict__ woT) {
  __shared__ u16 tile[64][66];
  const int blk = blockIdx.x, tid = threadIdx.x;
  if (blk < 8192) {
    int i = blk * 256 + tid;
    float4 v = ((const float4*)x)[i];
    ushort4 o;
    o.x = f2bf(v.x); o.y = f2bf(v.y); o.z = f2bf(v.z); o.w = f2bf(v.w);
    ((ushort4*)xb)[i] = o;
  } else if (blk < 8960) {
    int b2 = blk - 8192;
    int p = b2 >> 8, h = (b2 >> 4) & 15, e0 = (b2 & 15) * 64;
    const float* src = (p == 0 ? Wq : (p == 1 ? Wk : Wv)) + h * (E_ * DH_);
#pragma unroll
    for (int r = 0; r < 16; ++r) {
      int idx = r * 256 + tid;
      int el = idx >> 6, d = idx & 63;
      tile[el][d] = f2bf(src[(e0 + el) * DH_ + d]);
    }
    __syncthreads();
    u16* dst = wqkvT + (p * HD_ + h * DH_) * E_;
#pragma unroll
    for (int r = 0; r < 16; ++r) {
      int idx = r * 256 + tid;
      int d = idx >> 6, el = idx & 63;
      dst[d * E_ + e0 + el] = tile[el][d];
    }
  } else {
    int b3 = blk - 8960;
    int c0 = (b3 >> 4) * 64, e0 = (b3 & 15) * 64;
#pragma unroll
    for (int r = 0; r < 16; ++r) {
      int idx = r * 256 + tid;
      int cl = idx >> 6, el = idx & 63;
      tile[cl][el] = f2bf(Wo[(c0 + cl) * E_ + e0 + el]);
    }
    __syncthreads();
#pragma unroll
    for (int r = 0; r < 16; ++r) {
      int idx = r * 256 + tid;
      int er = idx >> 6, cl = idx & 63;
      woT[(e0 + er) * HD_ + c0 + cl] = tile[cl][er];
    }
  }
}

// ---- V transpose: [b,s,h,d] -> [b,h,d,s] (all stores/loads coalesced 16B) ----
__global__ __launch_bounds__(256) void transpose_v_kernel(
    const u16* __restrict__ vin, u16* __restrict__ vout) {
  __shared__ u16 t[64][72];
  const int tid = threadIdx.x;
  const int bh = blockIdx.y, st = blockIdx.x * 64;
  const u16* src = vin + ((size_t)((bh >> 4) * S_ + st)) * HD_ + (bh & 15) * 64;
#pragma unroll
  for (int rr = 0; rr < 2; ++rr) {
    int idx = rr * 256 + tid;
    int s = idx >> 3, ch = idx & 7;
    *(uint4*)&t[s][ch * 8] = *(const uint4*)(src + s * HD_ + ch * 8);
  }
  __syncthreads();
  u16* dst = vout + ((size_t)bh) * DH_ * S_ + st;
#pragma unroll
  for (int rr = 0; rr < 2; ++rr) {
    int idx = rr * 256 + tid;
    int d = idx >> 3, sc = (idx & 7) * 8;
    ushort4 o0, o1;
    o0.x = t[sc + 0][d]; o0.y = t[sc + 1][d]; o0.z = t[sc + 2][d]; o0.w = t[sc + 3][d];
    o1.x = t[sc + 4][d]; o1.y = t[sc + 5][d]; o1.z = t[sc + 6][d]; o1.w = t[sc + 7][d];
    *(ushort4*)(dst + (size_t)d * S_ + sc) = o0;
    *(ushort4*)(dst + (size_t)d * S_ + sc + 4) = o1;
  }
}

// ---------------- GEMM: C[M][N] = A[M][K] * Bt[N][K]^T, K = 1024, BK = 64 ----
// BK=64 single-buffer: 32 MFMA per barrier-pair (was 16) — halves the number
// of full vmcnt drains per block (K=1024 -> 16 iters, 32 barriers total).
// MODE 0: QKV epilogue — per-projection bias + bf16 store, coalesced [m][cc].
// MODE 1: out-proj epilogue (b0=bo; bias + fp32 store)
template <int MODE>
__global__ __launch_bounds__(256) void gemm_bt_kernel(
    const u16* __restrict__ A, const u16* __restrict__ Bt,
    const float* __restrict__ b0, const float* __restrict__ b1,
    const float* __restrict__ b2,
    u16* __restrict__ oQ, u16* __restrict__ oK, u16* __restrict__ oV,
    float* __restrict__ oF) {
  constexpr int K = 1024;
  __shared__ __align__(16) u16 As[128 * 64];   // 16 KB
  __shared__ __align__(16) u16 Bs[128 * 64];   // 16 KB
  const int tid = threadIdx.x;
  const int lane = tid & 63, wv = tid >> 6;
  const int wm = (wv >> 1) * 64, wn = (wv & 1) * 64;
  const int q4 = lane >> 4, lm = lane & 15;
  const int tileM = blockIdx.y * 128, tileN = blockIdx.x * 128;

  // staging: 4 rounds x 256 threads cover 128 rows x 8 chunks (16B each)
  const u16* gA[4]; const u16* gB[4]; u16* lA[4]; u16* lB[4];
#pragma unroll
  for (int rr = 0; rr < 4; ++rr) {
    int c = rr * 256 + tid;
    int r = c >> 3, sw = ((c & 7) ^ (r & 7)) * 8;
    gA[rr] = A + (size_t)(tileM + r) * K + sw;
    gB[rr] = Bt + (size_t)(tileN + r) * K + sw;
    lA[rr] = As + c * 8;
    lB[rr] = Bs + c * 8;
  }

  f32x4 acc[4][4] = {};

  int aoff[2][4], boff[2][4];
#pragma unroll
  for (int ks = 0; ks < 2; ++ks) {
#pragma unroll
    for (int i = 0; i < 4; ++i) {
      int ra = wm + i * 16 + lm;
      aoff[ks][i] = ra * 64 + (((ks * 4 + q4) ^ (ra & 7)) * 8);
      int rb = wn + i * 16 + lm;
      boff[ks][i] = rb * 64 + (((ks * 4 + q4) ^ (rb & 7)) * 8);
    }
  }

  for (int k0 = 0; k0 < K; k0 += 64) {
#pragma unroll
    for (int rr = 0; rr < 4; ++rr) {
      g2l16(gA[rr] + k0, lA[rr]);
      g2l16(gB[rr] + k0, lB[rr]);
    }
    __syncthreads();
#pragma unroll
    for (int ks = 0; ks < 2; ++ks) {
      bf16x8 af[4], bf[4];
#pragma unroll
      for (int i = 0; i < 4; ++i) af[i] = *(const bf16x8*)(As + aoff[ks][i]);
#pragma unroll
      for (int j = 0; j < 4; ++j) bf[j] = *(const bf16x8*)(Bs + boff[ks][j]);
#pragma unroll
      for (int i = 0; i < 4; ++i)
#pragma unroll
        for (int j = 0; j < 4; ++j)
          acc[i][j] = __builtin_amdgcn_mfma_f32_16x16x32_bf16(af[i], bf[j], acc[i][j], 0, 0, 0);
    }
    __syncthreads();
  }

#pragma unroll
  for (int j = 0; j < 4; ++j) {
    int n = tileN + wn + j * 16 + lm;
    float bs;
    int proj = 0, cc = n;
    if (MODE == 1) {
      bs = b0[n];
    } else {
      proj = n >> 10; cc = n & 1023;   // proj uniform per block (tileN 128-aligned)
      const float* bp = (proj == 0 ? b0 : (proj == 1 ? b1 : b2));
      bs = bp[cc];
    }
#pragma unroll
    for (int i = 0; i < 4; ++i) {
      int m0 = tileM + wm + i * 16 + q4 * 4;
      if (MODE == 1) {
#pragma unroll
        for (int r = 0; r < 4; ++r) oF[(m0 + r) * HD_ + n] = acc[i][j][r] + bs;
      } else {
        u16* optr = (proj == 0 ? oQ : (proj == 1 ? oK : oV));
        float scl = (proj == 0 ? QSCALE : 1.0f);
        f32x4 vv;
#pragma unroll
        for (int r = 0; r < 4; ++r) vv[r] = (acc[i][j][r] + bs) * scl;
        bf16x4 ov = __builtin_convertvector(vv, bf16x4);
        ushort4 us = *(ushort4*)&ov;
        optr[(m0 + 0) * 1024 + cc] = us.x;
        optr[(m0 + 1) * 1024 + cc] = us.y;
        optr[(m0 + 2) * 1024 + cc] = us.z;
        optr[(m0 + 3) * 1024 + cc] = us.w;
      }
    }
  }
}

// ---------------- flash attention ----------------
// Block: 256 q-rows of one (b,h); wave wv owns q-rows [wv*64, wv*64+64), all keys.
// K/V double-buffered in LDS via global_load_lds (one barrier per tile).
// KEY PERMUTATION: K rows staged at LDS slot s = kb*16+q4*4+r hold logical key
// kperm(s) = (kb&1)*32 + q4*8 + (kb>>1)*4 + r. With this order, the S^T-MFMA
// C-layout output IS the PV A-fragment layout per-lane (q=lm, keys ck*32+q4*8+j),
// and V keeps sequential key order. P never touches LDS.
// Interleaved per key-chunk (ck needs kb=ck and kb=ck+2) to cap register
// liveness; __launch_bounds__(256,2) — (256,3) forced spills (R6: 493 MB
// scratch WRITE_SIZE, 2.6x regression).
__global__ __launch_bounds__(256, 2) void flash_kernel(
    const u16* __restrict__ Q, const u16* __restrict__ Kb,
    const u16* __restrict__ Vt, u16* __restrict__ Z) {
  __shared__ __align__(16) u16 Ks[2][64 * 64];   // [slot][d] swizzled, key-permuted
  __shared__ __align__(16) u16 Vs[2][64 * 64];   // [d][key] swizzled, sequential
  const int tid = threadIdx.x, lane = tid & 63, wv = tid >> 6;
  const int q4 = lane >> 4, lm = lane & 15;

  const int bid = blockIdx.x;
  const int bh = bid >> 3, qt = bid & 7;         // 8 consecutive blocks share (b,h) K/V
  const int b = bh >> 4, h = bh & 15;

  const u16* qbase = Q + ((size_t)(b * S_ + qt * 256)) * HD_ + h * DH_;
  const u16* kbase = Kb + (size_t)b * S_ * HD_ + h * DH_;
  const u16* vbase = Vt + ((size_t)(b * H_ + h)) * DH_ * S_;
  u16* zbase = Z + ((size_t)(b * S_ + qt * 256)) * HD_ + h * DH_;

  // staging thread coords (slot row, swizzled source chunk), 2 rounds of 256
  const int c0 = tid,       r0 = c0 >> 3, s0 = ((c0 & 7) ^ (r0 & 7)) * 8;
  const int c1 = tid + 256, r1 = c1 >> 3, s1 = ((c1 & 7) ^ (r1 & 7)) * 8;
  // key permutation for K staging rows
  const int kr0 = ((r0 >> 4) & 1) * 32 + ((r0 >> 2) & 3) * 8 + (r0 >> 5) * 4 + (r0 & 3);
  const int kr1 = ((r1 >> 4) & 1) * 32 + ((r1 >> 2) & 3) * 8 + (r1 >> 5) * 4 + (r1 & 3);

  // persistent Q B-frags: q-row = wv*64 + qs*16 + lm, d = dc*32 + q4*8 ..+7
  bf16x8 qf[4][2];
#pragma unroll
  for (int qs = 0; qs < 4; ++qs)
#pragma unroll
    for (int dc = 0; dc < 2; ++dc)
      qf[qs][dc] = *(const bf16x8*)(qbase + (wv * 64 + qs * 16 + lm) * HD_ + dc * 32 + q4 * 8);

  const bf16x8 ones = {(__bf16)1.f, (__bf16)1.f, (__bf16)1.f, (__bf16)1.f,
                       (__bf16)1.f, (__bf16)1.f, (__bf16)1.f, (__bf16)1.f};

  // lane-constant LDS offsets (u16 units)
  int koff[4][2], voff[2][4];
#pragma unroll
  for (int kb = 0; kb < 4; ++kb)
#pragma unroll
    for (int dc = 0; dc < 2; ++dc) {
      int row = kb * 16 + lm;
      koff[kb][dc] = row * 64 + (((dc * 4 + q4) ^ (row & 7)) * 8);
    }
#pragma unroll
  for (int ck = 0; ck < 2; ++ck)
#pragma unroll
    for (int db = 0; db < 4; ++db) {
      int row = db * 16 + lm;
      voff[ck][db] = row * 64 + (((ck * 4 + q4) ^ (row & 7)) * 8);
    }

  f32x4 oacc[4][4] = {};
  f32x4 liacc[4] = {};

  // stage tile 0 into buffer 0
  {
    g2l16(kbase + kr0 * HD_ + s0, Ks[0] + c0 * 8);
    g2l16(kbase + kr1 * HD_ + s1, Ks[0] + c1 * 8);
    g2l16(vbase + r0 * S_ + s0, Vs[0] + c0 * 8);
    g2l16(vbase + r1 * S_ + s1, Vs[0] + c1 * 8);
  }

  for (int t = 0; t < 32; ++t) {
    const int pb = t & 1;
    __syncthreads();                      // staging of tile t complete
    if (t < 31) {                         // prefetch tile t+1 into the other buffer
      const u16* kt = kbase + (size_t)(t + 1) * 64 * HD_;
      const u16* vt = vbase + (t + 1) * 64;
      g2l16(kt + kr0 * HD_ + s0, Ks[1 - pb] + c0 * 8);
      g2l16(kt + kr1 * HD_ + s1, Ks[1 - pb] + c1 * 8);
      g2l16(vt + r0 * S_ + s0, Vs[1 - pb] + c0 * 8);
      g2l16(vt + r1 * S_ + s1, Vs[1 - pb] + c1 * 8);
    }
    const u16* Kp = Ks[pb];
    const u16* Vp = Vs[pb];

    // ---- per key-chunk ck (32 keys): S^T via kb={ck,ck+2}, exp2 in regs,
    //      then immediately PV — keeps only pf[4] live, not all 16 frags ----
#pragma unroll
    for (int ck = 0; ck < 2; ++ck) {
      bf16x8 ka0 = *(const bf16x8*)(Kp + koff[ck][0]);
      bf16x8 ka1 = *(const bf16x8*)(Kp + koff[ck][1]);
      bf16x8 kb0 = *(const bf16x8*)(Kp + koff[ck + 2][0]);
      bf16x8 kb1 = *(const bf16x8*)(Kp + koff[ck + 2][1]);
      bf16x8 pf[4];
#pragma unroll
      for (int qs = 0; qs < 4; ++qs) {
        f32x4 sa = {}, sb = {};
        sa = __builtin_amdgcn_mfma_f32_16x16x32_bf16(ka0, qf[qs][0], sa, 0, 0, 0);
        sa = __builtin_amdgcn_mfma_f32_16x16x32_bf16(ka1, qf[qs][1], sa, 0, 0, 0);
        sb = __builtin_amdgcn_mfma_f32_16x16x32_bf16(kb0, qf[qs][0], sb, 0, 0, 0);
        sb = __builtin_amdgcn_mfma_f32_16x16x32_bf16(kb1, qf[qs][1], sb, 0, 0, 0);
        f32x4 pa, pb2;
#pragma unroll
        for (int r = 0; r < 4; ++r) { pa[r] = EXP2F(sa[r]); pb2[r] = EXP2F(sb[r]); }
        bf16x4 la = __builtin_convertvector(pa, bf16x4);
        bf16x4 lb = __builtin_convertvector(pb2, bf16x4);
        pf[qs] = __builtin_shufflevector(la, lb, 0, 1, 2, 3, 4, 5, 6, 7);
      }
#pragma unroll
      for (int qs = 0; qs < 4; ++qs)
        liacc[qs] = __builtin_amdgcn_mfma_f32_16x16x32_bf16(pf[qs], ones, liacc[qs], 0, 0, 0);
#pragma unroll
      for (int db = 0; db < 4; ++db) {
        bf16x8 vf = *(const bf16x8*)(Vp + voff[ck][db]);
#pragma unroll
        for (int qs = 0; qs < 4; ++qs)
          oacc[qs][db] = __builtin_amdgcn_mfma_f32_16x16x32_bf16(pf[qs], vf, oacc[qs][db], 0, 0, 0);
      }
    }
  }

  // ---- normalize + store (wave owns its 64 q-rows; li is in-lane) ----
#pragma unroll
  for (int qs = 0; qs < 4; ++qs) {
    float rin[4];
#pragma unroll
    for (int r = 0; r < 4; ++r) rin[r] = 1.f / liacc[qs][r];
#pragma unroll
    for (int db = 0; db < 4; ++db) {
      f32x4 vv;
#pragma unroll
      for (int r = 0; r < 4; ++r) vv[r] = oacc[qs][db][r] * rin[r];
      bf16x4 ov = __builtin_convertvector(vv, bf16x4);
      ushort4 us = *(ushort4*)&ov;
      int m0 = wv * 64 + qs * 16 + q4 * 4;
      zbase[(m0 + 0) * HD_ + db * 16 + lm] = us.x;
      zbase[(m0 + 1) * HD_ + db * 16 + lm] = us.y;
      zbase[(m0 + 2) * HD_ + db * 16 + lm] = us.z;
      zbase[(m0 + 3) * HD_ + db * 16 + lm] = us.w;
    }
  }
}

// ---------------- host ----------------
extern "C" void kernel_launch(void* const* d_in, const int* in_sizes, int n_in,
                              void* d_out, int out_size, void* d_ws, size_t ws_size,
                              hipStream_t stream) {
  const float* x  = (const float*)d_in[0];
  const float* Wq = (const float*)d_in[1];
  const float* bq = (const float*)d_in[2];
  const float* Wk = (const float*)d_in[3];
  const float* bk = (const float*)d_in[4];
  const float* Wv = (const float*)d_in[5];
  const float* bv = (const float*)d_in[6];
  const float* Wo = (const float*)d_in[7];
  const float* bo = (const float*)d_in[8];
  float* out = (float*)d_out;

  char* w = (char*)d_ws;
  u16*   xb    = (u16*)w;   w += (size_t)M_ * E_ * 2;
  u16*   wqkvT = (u16*)w;   w += (size_t)3 * HD_ * E_ * 2;
  u16*   woT   = (u16*)w;   w += (size_t)E_ * HD_ * 2;
  u16*   qB    = (u16*)w;   w += (size_t)M_ * HD_ * 2;
  u16*   kB    = (u16*)w;   w += (size_t)M_ * HD_ * 2;
  u16*   vT    = (u16*)w;   w += (size_t)M_ * HD_ * 2;
  u16*   zB    = (u16*)w;   w += (size_t)M_ * HD_ * 2;
  // vB ([b,s,h,d] pre-transpose V) aliases zB: consumed by transpose_v before
  // flash writes zB.
  u16*   vB    = zB;

  prep_kernel<<<dim3(9216), 256, 0, stream>>>(x, Wq, Wk, Wv, Wo, xb, wqkvT, woT);
  gemm_bt_kernel<0><<<dim3(24, 64), 256, 0, stream>>>(xb, wqkvT, bq, bk, bv,
                                                      qB, kB, vB, nullptr);
  transpose_v_kernel<<<dim3(32, 64), 256, 0, stream>>>(vB, vT);
  flash_kernel<<<dim3(512), 256, 0, stream>>>(qB, kB, vT, zB);
  gemm_bt_kernel<1><<<dim3(8, 64), 256, 0, stream>>>(zB, woT, bo, nullptr, nullptr,
                                                     nullptr, nullptr, nullptr, out);
}